// Round 5
// baseline (3849.507 us; speedup 1.0000x reference)
//
#include <hip/hip_runtime.h>
#include <cstdint>
#include <cstddef>

// BooleanReservoir — persistent kernel, v8: BARRIER-FREE self-timed dataflow.
// lane = batch; states[node] = u64 (bit b = batch b).
// R9 structural change: no grid barrier of any kind. Per-step state buffers
// st[0..128] (no WAR hazards), each entry a 16B pair (D, G = D ^ KTAG).
// Consumers gather and retry until D^G == KTAG. Prefill: has-neigh entries
// (0, ~KTAG) = invalid; no-neigh/init/input entries = valid pairs.
// Tearing analysis (8B single-copy atomicity only):
//   (D_old=0, G_old=~K): 0^~K != K -> reject
//   (D_new, G_new):      D^D^K == K -> accept, correct
//   (D_new, G_old=~K):   accept iff D_new==~0 -> then D'=D_new correct
//   (D_old=0, G_new):    accept iff D_new==0  -> then D'=D_new correct
// => any accepted D is the producer's value. No fences, drains, flags, or
// syncthreads in the step loop; waves free-run (producer->consumer ~1 L3 RTT
// instead of the measured ~4.2 us/step grid rendezvous, invariant across 4
// barrier topologies in R1-R4).
// Deadlock-free: consumers wait only on step-t producers (DAG in t); all 512
// blocks co-resident (2/CU: 22.5KB LDS, 512 thr, 16 VGPR).

#define N_NODES   20000
#define N_INPUT   64
#define K_MAX     12
#define T_STEPS   128
#define N_BATCH   64
#define N_OUT     10
#define N_FEAT    (N_NODES - N_INPUT)   // 19936
#define DUMMY_NODE 20000                // always-zero, always-valid entry
#define ST_WORDS  20004
#define T_BUF     (T_STEPS + 1)         // st[0..128]

#define NBLK 512
#define NTHR 512                        // 8 waves/block, 2 blocks/CU
#define NPB  39                         // 512*39 = 19968 >= 19936
#define NPB_PAD 40                      // 8 waves * 5 nodes

#define KTAG 0x9E3779B97F4A7C15ull

#define RO_CHUNK 32                     // 19936 = 32 * 623
#define RO_NPC   623

typedef unsigned long long u64;

// ---------------- pack x: xp[t][b] = bits j of x[b][t][j] ----------------
__global__ __launch_bounds__(256) void pack_x_kernel(const int* __restrict__ x,
                                                     u64* __restrict__ xp) {
  const int t = blockIdx.x;
  const int wave = threadIdx.x >> 6, lane = threadIdx.x & 63;
  for (int b = wave; b < N_BATCH; b += 4) {
    int v = x[((size_t)b * T_STEPS + t) * 64 + lane];
    u64 bal = __ballot(v != 0);
    if (lane == 0) xp[(size_t)t * N_BATCH + b] = bal;
  }
}

// -------- init: wcol (input weight columns) --------
__global__ __launch_bounds__(256) void init_kernel(const int* __restrict__ w_in,
                                                   u64* __restrict__ wcol) {
  const int wave = threadIdx.x >> 6, lane = threadIdx.x & 63;
  for (int i = wave; i < 64; i += 4) {
    int wv = w_in[(size_t)lane * 64 + i];  // lane = j
    u64 wc = __ballot(wv != 0);
    if (lane == 0) wcol[i] = wc;
  }
}

// -------- u(t) for all t, written as VALID pairs into st[t][0..63] --------
__global__ __launch_bounds__(64) void u_pre_kernel(const u64* __restrict__ xp,
                                                   const u64* __restrict__ wcol,
                                                   u64* __restrict__ st) {
  const int t = blockIdx.x, lane = threadIdx.x;
  u64 xw = xp[(size_t)t * N_BATCH + lane];   // lane = batch
  for (int i = 0; i < 64; i++) {
    u64 ub = __ballot((xw & wcol[i]) != 0);
    if (lane == 0) {
      st[((size_t)t * ST_WORDS + i) * 2]     = ub;
      st[((size_t)t * ST_WORDS + i) * 2 + 1] = ub ^ KTAG;
    }
  }
}

// -------- prefill all 129 step buffers (pairs), re-run every call --------
// t=0: valid init pairs for every node (the initial state).
// t>=1: has-neigh -> INVALID (0, ~KTAG) (producer will write);
//       no-neigh  -> valid init pair (kept forever, matches reference);
//       dummy/pad -> valid (0, KTAG).
__global__ __launch_bounds__(512) void fill_kernel(const int* __restrict__ mask,
                                                   const int* __restrict__ inis,
                                                   u64* __restrict__ st) {
  int n = N_INPUT + blockIdx.x * 512 + threadIdx.x;   // [64, 20032)
  if (n >= ST_WORDS) return;
  bool hn = false; u64 iw = 0;
  if (n < N_NODES) {
    int h = 0;
    for (int j = 0; j < K_MAX; j++) h |= mask[(size_t)n * K_MAX + j];
    hn = (h != 0);
    iw = inis[n] ? ~0ull : 0ull;
  }
  const u64 dt0 = iw,             gt0 = iw ^ KTAG;
  const u64 dtr = hn ? 0ull : iw, gtr = hn ? ~KTAG : (iw ^ KTAG);
  const int t0 = blockIdx.y * 4, t1 = min(t0 + 4, T_BUF);
  for (int t = t0; t < t1; t++) {
    u64 d = (t == 0) ? dt0 : dtr, g = (t == 0) ? gt0 : gtr;
    st[((size_t)t * ST_WORDS + n) * 2]     = d;    // coalesced 16B/thread
    st[((size_t)t * ST_WORDS + n) * 2 + 1] = g;
  }
}

// ---- 64x64 bit transpose: lane l holds row l; returns lane b holding column b ----
__device__ __forceinline__ u64 bit_transpose64(u64 w, int lane) {
  const u64 LO0 = 0x00000000FFFFFFFFull, LO1 = 0x0000FFFF0000FFFFull,
            LO2 = 0x00FF00FF00FF00FFull, LO3 = 0x0F0F0F0F0F0F0F0Full,
            LO4 = 0x3333333333333333ull, LO5 = 0x5555555555555555ull;
#define XP_STAGE(d, LO)                                                  \
  {                                                                      \
    u64 p = (u64)__shfl_xor((long long)w, (d), 64);                      \
    if (lane & (d)) w = ((p >> (d)) & (LO)) | (w & ~(LO));               \
    else            w = (w & (LO)) | ((p << (d)) & ~(LO));               \
  }
  XP_STAGE(32, LO0) XP_STAGE(16, LO1) XP_STAGE(8, LO2)
  XP_STAGE(4,  LO3) XP_STAGE(2,  LO4) XP_STAGE(1, LO5)
#undef XP_STAGE
  return w;
}

// ---------------- persistent reservoir: 128 steps, self-timed ----------------
__global__ __launch_bounds__(NTHR, 4) void reservoir_kernel(
    const int* __restrict__ lut, const int* __restrict__ adj,
    const int* __restrict__ mask, u64* __restrict__ st) {
  __shared__ u64 lut_lds[NPB_PAD * 64];        // 20480 B
  __shared__ int adj_lds[NPB_PAD * K_MAX];     //  1920 B
  __shared__ unsigned char hn_lds[NPB_PAD];

  const int bi = blockIdx.x;
  const int tid = threadIdx.x;
  const int wave = tid >> 6, lane = tid & 63;
  const int base = N_INPUT + bi * NPB;
  const int nloc = min(NPB, N_NODES - base);   // last block: 7

  // ---- prologue: adjacency (slot-REVERSED: slot j at offset 11-j) + hn ----
  if (tid < NPB_PAD) {
    int i = tid, h = 0;
    if (i < nloc) {
      for (int j = 0; j < K_MAX; j++) {
        int m = mask[(size_t)(base + i) * K_MAX + j];
        int a = adj[(size_t)(base + i) * K_MAX + j];
        adj_lds[i * K_MAX + (K_MAX - 1 - j)] = m ? a : DUMMY_NODE;
        h |= m;
      }
    } else {
      for (int j = 0; j < K_MAX; j++) adj_lds[i * K_MAX + j] = DUMMY_NODE;
    }
    hn_lds[i] = (unsigned char)(h ? 1 : 0);
  }

  // ---- prologue: pack this block's LUT slice into LDS (proven v4 path) ----
  const int nwords = nloc * 64;
  const int* lp = lut + (size_t)base * 4096;
  for (int w0 = wave * 8; w0 < nwords; w0 += 64) {
    int v[8];
#pragma unroll
    for (int q = 0; q < 8; q++) {
      int widx = w0 + q;
      v[q] = (widx < nwords) ? lp[(size_t)widx * 64 + lane] : 0;   // coalesced 256B
    }
#pragma unroll
    for (int q = 0; q < 8; q++) {
      int widx = w0 + q;
      u64 bal = __ballot(v[q] != 0);
      if (lane == 0 && widx < nwords) lut_lds[widx] = bal;
    }
  }
  __syncthreads();   // block-local only; after this, waves free-run

  const int l0 = wave * 5;                     // this wave's first local node
  const int cnt = min(5, nloc - l0);           // may be <= 0

  int a0 = DUMMY_NODE;                         // lanes 60-63 gather the 0-word
  if (lane < 60) a0 = adj_lds[l0 * K_MAX + lane];
  unsigned hmask = 0;
#pragma unroll
  for (int i = 0; i < 5; i++) hmask |= (unsigned)hn_lds[l0 + i] << i;

  // ---- 128 self-timed steps: gather-validate -> transpose -> LUT -> store ----
  for (int t = 0; t < T_STEPS; t++) {
    u64* stc = st + (size_t)t * ST_WORDS * 2;
    u64* stn = st + (size_t)(t + 1) * ST_WORDS * 2;

    u64 d = __hip_atomic_load(&stc[2 * a0],     __ATOMIC_RELAXED, __HIP_MEMORY_SCOPE_AGENT);
    u64 g = __hip_atomic_load(&stc[2 * a0 + 1], __ATOMIC_RELAXED, __HIP_MEMORY_SCOPE_AGENT);
    while (!__all((d ^ g) == KTAG)) {
      d = __hip_atomic_load(&stc[2 * a0],     __ATOMIC_RELAXED, __HIP_MEMORY_SCOPE_AGENT);
      g = __hip_atomic_load(&stc[2 * a0 + 1], __ATOMIC_RELAXED, __HIP_MEMORY_SCOPE_AGENT);
    }
    // transpose: lane b now holds all 60 index bits for batch b
    u64 w = bit_transpose64(d, lane);

#pragma unroll
    for (int i = 0; i < 5; i++) {
      if (i < cnt) {                           // wave-uniform
        unsigned idx = (unsigned)(w >> (12 * i)) & 0xFFFu;   // MSB-first index
        u64 gl = lut_lds[(l0 + i) * 64 + (idx >> 6)];
        u64 res = __ballot((gl >> (idx & 63)) & 1ull);
        if (lane == 0 && ((hmask >> i) & 1u)) {
          __hip_atomic_store(&stn[2 * (base + l0 + i)], res,
                             __ATOMIC_RELAXED, __HIP_MEMORY_SCOPE_AGENT);
          __hip_atomic_store(&stn[2 * (base + l0 + i) + 1], res ^ KTAG,
                             __ATOMIC_RELAXED, __HIP_MEMORY_SCOPE_AGENT);
        }
      }
    }
  }
}

// ---- readout part: partial[c][o][b] = sum over chunk c of W[o][n]*bit(n,b) ----
__global__ __launch_bounds__(256) void readout_part(const u64* __restrict__ st128,
                                                    const float* __restrict__ Wout,
                                                    float* __restrict__ partial) {
  const int c = blockIdx.x / N_OUT;            // 0..31
  const int o = blockIdx.x % N_OUT;
  const int b = threadIdx.x & 63, k = threadIdx.x >> 6;   // lane = batch
  const int n0 = c * RO_NPC, n1 = n0 + RO_NPC;
  float acc = 0.f;
  for (int n = n0 + k; n < n1; n += 4) {
    u64 s = st128[2 * (N_INPUT + n)];          // D half; wave-uniform broadcast
    float w = Wout[(size_t)o * N_FEAT + n];
    acc += ((s >> b) & 1ull) ? w : 0.f;
  }
  __shared__ float red[4][64];
  red[k][b] = acc;
  __syncthreads();
  if (threadIdx.x < 64) {
    float tot = red[0][b] + red[1][b] + red[2][b] + red[3][b];
    partial[((size_t)c * N_OUT + o) * 64 + b] = tot;
  }
}

// ---- readout final: out[b][o] = sigmoid(sum_c partial + bias) ----
__global__ __launch_bounds__(640) void readout_final(const float* __restrict__ partial,
                                                     const float* __restrict__ bout,
                                                     float* __restrict__ out) {
  const int b = threadIdx.x & 63, o = threadIdx.x >> 6;   // 640 threads
  float tot = bout[o];
  for (int c = 0; c < RO_CHUNK; c++)
    tot += partial[((size_t)c * N_OUT + o) * 64 + b];
  out[(size_t)b * N_OUT + o] = 1.f / (1.f + __expf(-tot));
}

extern "C" void kernel_launch(void* const* d_in, const int* in_sizes, int n_in,
                              void* d_out, int out_size, void* d_ws, size_t ws_size,
                              hipStream_t stream) {
  const int* x    = (const int*)d_in[0];
  const int* w_in = (const int*)d_in[1];
  const int* adj  = (const int*)d_in[2];
  const int* mask = (const int*)d_in[3];
  const int* lut  = (const int*)d_in[4];
  const int* inis = (const int*)d_in[5];
  const float* Wout = (const float*)d_in[6];
  const float* bout = (const float*)d_in[7];
  float* out = (float*)d_out;

  char* ws = (char*)d_ws;
  size_t off = 0;
  auto alloc = [&](size_t bytes) -> void* {
    void* p = ws + off;
    off += (bytes + 255) & ~(size_t)255;
    return p;
  };
  u64* st_all = (u64*)alloc((size_t)T_BUF * ST_WORDS * 16);   // 41.3 MB (pairs)
  u64* xp     = (u64*)alloc((size_t)T_STEPS * N_BATCH * 8);
  u64* wcol   = (u64*)alloc(64 * 8);
  float* partial = (float*)alloc((size_t)RO_CHUNK * N_OUT * 64 * 4);  // 80 KB
  (void)ws_size; (void)in_sizes; (void)n_in; (void)out_size;

  hipLaunchKernelGGL(pack_x_kernel, dim3(T_STEPS), dim3(256), 0, stream, x, xp);
  hipLaunchKernelGGL(init_kernel, dim3(1), dim3(256), 0, stream, w_in, wcol);
  hipLaunchKernelGGL(fill_kernel, dim3(39, 33), dim3(512), 0, stream,
                     mask, inis, st_all);
  hipLaunchKernelGGL(u_pre_kernel, dim3(T_STEPS), dim3(64), 0, stream,
                     xp, wcol, st_all);

  hipLaunchKernelGGL(reservoir_kernel, dim3(NBLK), dim3(NTHR), 0, stream,
                     lut, adj, mask, st_all);

  // final states live in st[128] (D halves)
  hipLaunchKernelGGL(readout_part, dim3(RO_CHUNK * N_OUT), dim3(256), 0, stream,
                     st_all + (size_t)T_STEPS * ST_WORDS * 2, Wout, partial);
  hipLaunchKernelGGL(readout_final, dim3(1), dim3(640), 0, stream,
                     partial, bout, out);
}

// Round 6
// 3017.941 us; speedup vs baseline: 1.2755x; 1.2755x over previous
//
#include <hip/hip_runtime.h>
#include <cstdint>
#include <cstddef>

// BooleanReservoir — persistent kernel, v9: PACED self-timed dataflow.
// lane = batch; states[node] = u64 (bit b = batch b).
// Hybrid of v8 (tag-validated per-step buffers; consumers accept data ~1 L3 RTT
// after the producer's store lands — correctness-proven in R5) and v4's relay
// barrier (best-measured rendezvous), used ONLY as pacing every PACE=4 steps.
// R5 failure mode was congestion collapse: unpaced waves spread out and 4096
// validation loops x 60 scattered pair-fetches saturated the fabric (FETCH 1 GB,
// 27.5 us/step). Pacing bounds skew to <= PACE steps -> retry rounds stay O(1).
// The barrier carries NO data-correctness duty (validation does), so its
// amortized cost is ~4.2/PACE us/step.
// Tearing analysis for (D, G=D^KTAG) pairs (8B single-copy atomicity only):
//   (D_old=0, G_old=~K): reject.  (D_new, G_new): accept, correct.
//   (D_new, G_old=~K): accept iff D_new==~0 -> correct.
//   (D_old=0, G_new):  accept iff D_new==0  -> correct.
// Deadlock-free: validation waits only on step-t producers (DAG in t); pacing
// barrier waits only on blocks completing their window (same DAG); all 512
// blocks co-resident (2/CU: 22.5 KB LDS, 512 thr, 16 VGPR).

#define N_NODES   20000
#define N_INPUT   64
#define K_MAX     12
#define T_STEPS   128
#define N_BATCH   64
#define N_OUT     10
#define N_FEAT    (N_NODES - N_INPUT)   // 19936
#define DUMMY_NODE 20000                // always-zero, always-valid entry
#define ST_WORDS  20004
#define T_BUF     (T_STEPS + 1)         // st[0..128]

#define NBLK 512
#define NTHR 512                        // 8 waves/block, 2 blocks/CU
#define NPB  39                         // 512*39 = 19968 >= 19936
#define NPB_PAD 40                      // 8 waves * 5 nodes

#define PACE 4                          // steps per pacing rendezvous
#define BAR_CNT 64                      // distributed arrival counters
#define GO_CNT  8                       // go-flags (release fan-out)
#define BAR_STRIDE 32                   // u32 units -> 128 B apart

#define KTAG 0x9E3779B97F4A7C15ull

#define RO_CHUNK 32                     // 19936 = 32 * 623
#define RO_NPC   623

typedef unsigned long long u64;

// ---------------- pack x: xp[t][b] = bits j of x[b][t][j] ----------------
__global__ __launch_bounds__(256) void pack_x_kernel(const int* __restrict__ x,
                                                     u64* __restrict__ xp) {
  const int t = blockIdx.x;
  const int wave = threadIdx.x >> 6, lane = threadIdx.x & 63;
  for (int b = wave; b < N_BATCH; b += 4) {
    int v = x[((size_t)b * T_STEPS + t) * 64 + lane];
    u64 bal = __ballot(v != 0);
    if (lane == 0) xp[(size_t)t * N_BATCH + b] = bal;
  }
}

// -------- init: wcol (input weight columns) + zero barrier counters/go --------
__global__ __launch_bounds__(256) void init_kernel(const int* __restrict__ w_in,
                                                   u64* __restrict__ wcol,
                                                   unsigned* __restrict__ bar) {
  if (blockIdx.x == 0) {
    const int wave = threadIdx.x >> 6, lane = threadIdx.x & 63;
    for (int i = wave; i < 64; i += 4) {
      int wv = w_in[(size_t)lane * 64 + i];  // lane = j
      u64 wc = __ballot(wv != 0);
      if (lane == 0) wcol[i] = wc;
    }
  } else {
    if (threadIdx.x < BAR_CNT + GO_CNT)      // ws re-poisoned each call
      bar[threadIdx.x * BAR_STRIDE] = 0u;
  }
}

// -------- u(t) for all t, written as VALID pairs into st[t][0..63] --------
__global__ __launch_bounds__(64) void u_pre_kernel(const u64* __restrict__ xp,
                                                   const u64* __restrict__ wcol,
                                                   u64* __restrict__ st) {
  const int t = blockIdx.x, lane = threadIdx.x;
  u64 xw = xp[(size_t)t * N_BATCH + lane];   // lane = batch
  for (int i = 0; i < 64; i++) {
    u64 ub = __ballot((xw & wcol[i]) != 0);
    if (lane == 0) {
      st[((size_t)t * ST_WORDS + i) * 2]     = ub;
      st[((size_t)t * ST_WORDS + i) * 2 + 1] = ub ^ KTAG;
    }
  }
}

// -------- prefill all 129 step buffers (pairs), re-run every call --------
// t=0: valid init pairs. t>=1: has-neigh -> INVALID (0, ~KTAG);
// no-neigh -> valid init pair (kept forever); dummy/pad -> valid (0, KTAG).
__global__ __launch_bounds__(512) void fill_kernel(const int* __restrict__ mask,
                                                   const int* __restrict__ inis,
                                                   u64* __restrict__ st) {
  int n = N_INPUT + blockIdx.x * 512 + threadIdx.x;   // [64, 20032)
  if (n >= ST_WORDS) return;
  bool hn = false; u64 iw = 0;
  if (n < N_NODES) {
    int h = 0;
    for (int j = 0; j < K_MAX; j++) h |= mask[(size_t)n * K_MAX + j];
    hn = (h != 0);
    iw = inis[n] ? ~0ull : 0ull;
  }
  const u64 dt0 = iw,             gt0 = iw ^ KTAG;
  const u64 dtr = hn ? 0ull : iw, gtr = hn ? ~KTAG : (iw ^ KTAG);
  const int t0 = blockIdx.y * 4, t1 = min(t0 + 4, T_BUF);
  for (int t = t0; t < t1; t++) {
    u64 d = (t == 0) ? dt0 : dtr, g = (t == 0) ? gt0 : gtr;
    st[((size_t)t * ST_WORDS + n) * 2]     = d;    // coalesced 16B/thread
    st[((size_t)t * ST_WORDS + n) * 2 + 1] = g;
  }
}

// ---- 64x64 bit transpose: lane l holds row l; returns lane b holding column b ----
__device__ __forceinline__ u64 bit_transpose64(u64 w, int lane) {
  const u64 LO0 = 0x00000000FFFFFFFFull, LO1 = 0x0000FFFF0000FFFFull,
            LO2 = 0x00FF00FF00FF00FFull, LO3 = 0x0F0F0F0F0F0F0F0Full,
            LO4 = 0x3333333333333333ull, LO5 = 0x5555555555555555ull;
#define XP_STAGE(d, LO)                                                  \
  {                                                                      \
    u64 p = (u64)__shfl_xor((long long)w, (d), 64);                      \
    if (lane & (d)) w = ((p >> (d)) & (LO)) | (w & ~(LO));               \
    else            w = (w & (LO)) | ((p << (d)) & ~(LO));               \
  }
  XP_STAGE(32, LO0) XP_STAGE(16, LO1) XP_STAGE(8, LO2)
  XP_STAGE(4,  LO3) XP_STAGE(2,  LO4) XP_STAGE(1, LO5)
#undef XP_STAGE
  return w;
}

// ---------------- persistent reservoir: 128 steps, paced dataflow ----------------
__global__ __launch_bounds__(NTHR, 4) void reservoir_kernel(
    const int* __restrict__ lut, const int* __restrict__ adj,
    const int* __restrict__ mask, u64* __restrict__ st,
    unsigned* __restrict__ bar) {
  __shared__ u64 lut_lds[NPB_PAD * 64];        // 20480 B
  __shared__ int adj_lds[NPB_PAD * K_MAX];     //  1920 B
  __shared__ unsigned char hn_lds[NPB_PAD];

  const int bi = blockIdx.x;
  const int tid = threadIdx.x;
  const int wave = tid >> 6, lane = tid & 63;
  const int base = N_INPUT + bi * NPB;
  const int nloc = min(NPB, N_NODES - base);   // last block: 7

  // ---- prologue: adjacency (slot-REVERSED: slot j at offset 11-j) + hn ----
  if (tid < NPB_PAD) {
    int i = tid, h = 0;
    if (i < nloc) {
      for (int j = 0; j < K_MAX; j++) {
        int m = mask[(size_t)(base + i) * K_MAX + j];
        int a = adj[(size_t)(base + i) * K_MAX + j];
        adj_lds[i * K_MAX + (K_MAX - 1 - j)] = m ? a : DUMMY_NODE;
        h |= m;
      }
    } else {
      for (int j = 0; j < K_MAX; j++) adj_lds[i * K_MAX + j] = DUMMY_NODE;
    }
    hn_lds[i] = (unsigned char)(h ? 1 : 0);
  }

  // ---- prologue: pack this block's LUT slice into LDS (proven v4 path) ----
  const int nwords = nloc * 64;
  const int* lp = lut + (size_t)base * 4096;
  for (int w0 = wave * 8; w0 < nwords; w0 += 64) {
    int v[8];
#pragma unroll
    for (int q = 0; q < 8; q++) {
      int widx = w0 + q;
      v[q] = (widx < nwords) ? lp[(size_t)widx * 64 + lane] : 0;   // coalesced 256B
    }
#pragma unroll
    for (int q = 0; q < 8; q++) {
      int widx = w0 + q;
      u64 bal = __ballot(v[q] != 0);
      if (lane == 0 && widx < nwords) lut_lds[widx] = bal;
    }
  }
  __syncthreads();   // block-local only

  const int l0 = wave * 5;                     // this wave's first local node
  const int cnt = min(5, nloc - l0);           // may be <= 0

  int a0 = DUMMY_NODE;                         // lanes 60-63 gather the 0-word
  if (lane < 60) a0 = adj_lds[l0 * K_MAX + lane];
  unsigned hmask = 0;
#pragma unroll
  for (int i = 0; i < 5; i++) hmask |= (unsigned)hn_lds[l0 + i] << i;

  // ---- 128 steps: validated gather -> compute -> store; pacing every PACE ----
  for (int t = 0; t < T_STEPS; t++) {
    u64* stc = st + (size_t)t * ST_WORDS * 2;
    u64* stn = st + (size_t)(t + 1) * ST_WORDS * 2;

    // gather + validate (accepts data ~1 RTT after the producer's store lands)
    u64 d = __hip_atomic_load(&stc[2 * a0],     __ATOMIC_RELAXED, __HIP_MEMORY_SCOPE_AGENT);
    u64 g = __hip_atomic_load(&stc[2 * a0 + 1], __ATOMIC_RELAXED, __HIP_MEMORY_SCOPE_AGENT);
    while (!__all((d ^ g) == KTAG)) {
      d = __hip_atomic_load(&stc[2 * a0],     __ATOMIC_RELAXED, __HIP_MEMORY_SCOPE_AGENT);
      g = __hip_atomic_load(&stc[2 * a0 + 1], __ATOMIC_RELAXED, __HIP_MEMORY_SCOPE_AGENT);
    }
    u64 w = bit_transpose64(d, lane);          // lane b: 60 index bits for batch b

#pragma unroll
    for (int i = 0; i < 5; i++) {
      if (i < cnt) {                           // wave-uniform
        unsigned idx = (unsigned)(w >> (12 * i)) & 0xFFFu;   // MSB-first index
        u64 gl = lut_lds[(l0 + i) * 64 + (idx >> 6)];
        u64 res = __ballot((gl >> (idx & 63)) & 1ull);
        if (lane == 0 && ((hmask >> i) & 1u)) {
          __hip_atomic_store(&stn[2 * (base + l0 + i)], res,
                             __ATOMIC_RELAXED, __HIP_MEMORY_SCOPE_AGENT);
          __hip_atomic_store(&stn[2 * (base + l0 + i) + 1], res ^ KTAG,
                             __ATOMIC_RELAXED, __HIP_MEMORY_SCOPE_AGENT);
        }
      }
    }

    // ---- pacing rendezvous every PACE steps (no data-correctness duty) ----
    if (((t + 1) & (PACE - 1)) == 0 && t + 1 < T_STEPS) {
      const unsigned r = (unsigned)((t + 1) / PACE);
      __syncthreads();
      if (tid == 0)
        __hip_atomic_fetch_add(&bar[(bi & (BAR_CNT - 1)) * BAR_STRIDE], 1u,
                               __ATOMIC_RELAXED, __HIP_MEMORY_SCOPE_AGENT);
      if (bi == 0 && wave == 0) {
        const unsigned tgt = r * (NBLK / BAR_CNT);
        for (;;) {
          unsigned c = __hip_atomic_load(&bar[lane * BAR_STRIDE],
                                         __ATOMIC_RELAXED, __HIP_MEMORY_SCOPE_AGENT);
          if (__all(c >= tgt)) break;
        }
        if (lane < GO_CNT)
          __hip_atomic_store(&bar[(BAR_CNT + lane) * BAR_STRIDE], r,
                             __ATOMIC_RELAXED, __HIP_MEMORY_SCOPE_AGENT);
      } else if (wave == 0) {
        unsigned* gp = &bar[(BAR_CNT + (bi & (GO_CNT - 1))) * BAR_STRIDE];
        while (__hip_atomic_load(gp, __ATOMIC_RELAXED, __HIP_MEMORY_SCOPE_AGENT)
               < r) { /* spin */ }
      }
      __syncthreads();
    }
  }
}

// ---- readout part: partial[c][o][b] = sum over chunk c of W[o][n]*bit(n,b) ----
__global__ __launch_bounds__(256) void readout_part(const u64* __restrict__ st128,
                                                    const float* __restrict__ Wout,
                                                    float* __restrict__ partial) {
  const int c = blockIdx.x / N_OUT;            // 0..31
  const int o = blockIdx.x % N_OUT;
  const int b = threadIdx.x & 63, k = threadIdx.x >> 6;   // lane = batch
  const int n0 = c * RO_NPC, n1 = n0 + RO_NPC;
  float acc = 0.f;
  for (int n = n0 + k; n < n1; n += 4) {
    u64 s = st128[2 * (N_INPUT + n)];          // D half; wave-uniform broadcast
    float w = Wout[(size_t)o * N_FEAT + n];
    acc += ((s >> b) & 1ull) ? w : 0.f;
  }
  __shared__ float red[4][64];
  red[k][b] = acc;
  __syncthreads();
  if (threadIdx.x < 64) {
    float tot = red[0][b] + red[1][b] + red[2][b] + red[3][b];
    partial[((size_t)c * N_OUT + o) * 64 + b] = tot;
  }
}

// ---- readout final: out[b][o] = sigmoid(sum_c partial + bias) ----
__global__ __launch_bounds__(640) void readout_final(const float* __restrict__ partial,
                                                     const float* __restrict__ bout,
                                                     float* __restrict__ out) {
  const int b = threadIdx.x & 63, o = threadIdx.x >> 6;   // 640 threads
  float tot = bout[o];
  for (int c = 0; c < RO_CHUNK; c++)
    tot += partial[((size_t)c * N_OUT + o) * 64 + b];
  out[(size_t)b * N_OUT + o] = 1.f / (1.f + __expf(-tot));
}

extern "C" void kernel_launch(void* const* d_in, const int* in_sizes, int n_in,
                              void* d_out, int out_size, void* d_ws, size_t ws_size,
                              hipStream_t stream) {
  const int* x    = (const int*)d_in[0];
  const int* w_in = (const int*)d_in[1];
  const int* adj  = (const int*)d_in[2];
  const int* mask = (const int*)d_in[3];
  const int* lut  = (const int*)d_in[4];
  const int* inis = (const int*)d_in[5];
  const float* Wout = (const float*)d_in[6];
  const float* bout = (const float*)d_in[7];
  float* out = (float*)d_out;

  char* ws = (char*)d_ws;
  size_t off = 0;
  auto alloc = [&](size_t bytes) -> void* {
    void* p = ws + off;
    off += (bytes + 255) & ~(size_t)255;
    return p;
  };
  u64* st_all = (u64*)alloc((size_t)T_BUF * ST_WORDS * 16);   // 41.3 MB (pairs)
  u64* xp     = (u64*)alloc((size_t)T_STEPS * N_BATCH * 8);
  u64* wcol   = (u64*)alloc(64 * 8);
  unsigned* bar = (unsigned*)alloc((size_t)(BAR_CNT + GO_CNT) * BAR_STRIDE * 4);
  float* partial = (float*)alloc((size_t)RO_CHUNK * N_OUT * 64 * 4);  // 80 KB
  (void)ws_size; (void)in_sizes; (void)n_in; (void)out_size;

  hipLaunchKernelGGL(pack_x_kernel, dim3(T_STEPS), dim3(256), 0, stream, x, xp);
  hipLaunchKernelGGL(init_kernel, dim3(2), dim3(256), 0, stream, w_in, wcol, bar);
  hipLaunchKernelGGL(fill_kernel, dim3(39, 33), dim3(512), 0, stream,
                     mask, inis, st_all);
  hipLaunchKernelGGL(u_pre_kernel, dim3(T_STEPS), dim3(64), 0, stream,
                     xp, wcol, st_all);

  hipLaunchKernelGGL(reservoir_kernel, dim3(NBLK), dim3(NTHR), 0, stream,
                     lut, adj, mask, st_all, bar);

  // final states live in st[128] (D halves)
  hipLaunchKernelGGL(readout_part, dim3(RO_CHUNK * N_OUT), dim3(256), 0, stream,
                     st_all + (size_t)T_STEPS * ST_WORDS * 2, Wout, partial);
  hipLaunchKernelGGL(readout_final, dim3(1), dim3(640), 0, stream,
                     partial, bout, out);
}

// Round 8
// 1789.577 us; speedup vs baseline: 2.1511x; 1.6864x over previous
//
#include <hip/hip_runtime.h>
#include <cstdint>
#include <cstddef>

// BooleanReservoir — persistent kernel, v11: paced self-timed dataflow with
// v4-PROVEN pacing-plane traffic shape (block-aggregated arrivals, LDS gate
// broadcast, pacemaker relay), all OFF the data critical path.
// lane = batch; states[node] = u64 (bit b = batch b).
// Data plane (proven correct R5/R6): per-step buffers st[0..128] of (D, G=D^KTAG)
// pairs; consumers accept a gather once D^G==KTAG (masked per-lane retry with
// s_sleep backoff -> no R5-style 120-req/round congestion spiral).
// Pacing plane (new in this round, but every global-traffic pattern is one v4
// already measured): per-window LDS arrival counters; the LAST wave of a block
// to finish window w does ONE global fetch_add (512 RMW/window = 8/line) and is
// the block's gate-master: it alone polls the go replica (64 readers/line),
// then LDS-broadcasts. Pacemaker block scans 64 counters, publishes go rounds
// (= v4's leader relay, running concurrently with compute).
// Lagged gate: entering window w+1 requires go >= w (all waves finished w-1);
// skew <= 2 windows = 8 steps. Gates carry no data-correctness duty.
// Deadlock-free (induction on min-progress wave): validation for step t needs
// only stores already issued by waves at progress >= t-1; gate for window w
// needs only arrivals already issued by all waves (p_min = 4w+3 > 4w-1); all
// fired stores/RMWs land in finite time; pacemaker targets all satisfiable.
// 513 blocks co-resident: 4 blk/CU by threads (2048/512), 7 by LDS -> 1024 slots.

#define N_NODES   20000
#define N_INPUT   64
#define K_MAX     12
#define T_STEPS   128
#define N_BATCH   64
#define N_OUT     10
#define N_FEAT    (N_NODES - N_INPUT)   // 19936
#define DUMMY_NODE 20000                // always-zero, always-valid entry
#define ST_WORDS  20004
#define T_BUF     (T_STEPS + 1)         // st[0..128]

#define NCOMP 512                       // compute blocks
#define NBLK  (NCOMP + 1)               // + pacemaker (last block)
#define NTHR 512                        // 8 waves/block
#define NPB  39                         // 512*39 = 19968 >= 19936
#define NPB_PAD 40                      // 8 waves * 5 nodes

#define PACE 4                          // steps per window
#define NWIN (T_STEPS / PACE)           // 32 windows (0..31)
#define BAR_CNT 64                      // arrival counters: 8 blocks/counter
#define GO_CNT  8                       // go replicas: 64 master-readers/line
#define BAR_STRIDE 32                   // u32 units -> 128 B apart

#define KTAG 0x9E3779B97F4A7C15ull

#define RO_CHUNK 32                     // 19936 = 32 * 623
#define RO_NPC   623

typedef unsigned long long u64;

#define ALOAD(p)    __hip_atomic_load((p),  __ATOMIC_RELAXED, __HIP_MEMORY_SCOPE_AGENT)
#define ASTORE(p,v) __hip_atomic_store((p), (v), __ATOMIC_RELAXED, __HIP_MEMORY_SCOPE_AGENT)

// ---------------- pack x: xp[t][b] = bits j of x[b][t][j] ----------------
__global__ __launch_bounds__(256) void pack_x_kernel(const int* __restrict__ x,
                                                     u64* __restrict__ xp) {
  const int t = blockIdx.x;
  const int wave = threadIdx.x >> 6, lane = threadIdx.x & 63;
  for (int b = wave; b < N_BATCH; b += 4) {
    int v = x[((size_t)b * T_STEPS + t) * 64 + lane];
    u64 bal = __ballot(v != 0);
    if (lane == 0) xp[(size_t)t * N_BATCH + b] = bal;
  }
}

// -------- init: wcol (input weight columns) + zero barrier counters/go --------
__global__ __launch_bounds__(256) void init_kernel(const int* __restrict__ w_in,
                                                   u64* __restrict__ wcol,
                                                   unsigned* __restrict__ bar) {
  if (blockIdx.x == 0) {
    const int wave = threadIdx.x >> 6, lane = threadIdx.x & 63;
    for (int i = wave; i < 64; i += 4) {
      int wv = w_in[(size_t)lane * 64 + i];  // lane = j
      u64 wc = __ballot(wv != 0);
      if (lane == 0) wcol[i] = wc;
    }
  } else {
    if (threadIdx.x < BAR_CNT + GO_CNT)      // ws re-poisoned each call
      bar[threadIdx.x * BAR_STRIDE] = 0u;
  }
}

// -------- u(t) for all t, written as VALID pairs into st[t][0..63] --------
__global__ __launch_bounds__(64) void u_pre_kernel(const u64* __restrict__ xp,
                                                   const u64* __restrict__ wcol,
                                                   u64* __restrict__ st) {
  const int t = blockIdx.x, lane = threadIdx.x;
  u64 xw = xp[(size_t)t * N_BATCH + lane];   // lane = batch
  for (int i = 0; i < 64; i++) {
    u64 ub = __ballot((xw & wcol[i]) != 0);
    if (lane == 0) {
      st[((size_t)t * ST_WORDS + i) * 2]     = ub;
      st[((size_t)t * ST_WORDS + i) * 2 + 1] = ub ^ KTAG;
    }
  }
}

// -------- prefill all 129 step buffers (pairs), re-run every call --------
// t=0: valid init pairs. t>=1: has-neigh -> INVALID (0, ~KTAG);
// no-neigh -> valid init pair (kept forever); dummy/pad -> valid (0, KTAG).
__global__ __launch_bounds__(512) void fill_kernel(const int* __restrict__ mask,
                                                   const int* __restrict__ inis,
                                                   u64* __restrict__ st) {
  int n = N_INPUT + blockIdx.x * 512 + threadIdx.x;   // [64, 20032)
  if (n >= ST_WORDS) return;
  bool hn = false; u64 iw = 0;
  if (n < N_NODES) {
    int h = 0;
    for (int j = 0; j < K_MAX; j++) h |= mask[(size_t)n * K_MAX + j];
    hn = (h != 0);
    iw = inis[n] ? ~0ull : 0ull;
  }
  const u64 dt0 = iw,             gt0 = iw ^ KTAG;
  const u64 dtr = hn ? 0ull : iw, gtr = hn ? ~KTAG : (iw ^ KTAG);
  const int t0 = blockIdx.y * 4, t1 = min(t0 + 4, T_BUF);
  for (int t = t0; t < t1; t++) {
    u64 d = (t == 0) ? dt0 : dtr, g = (t == 0) ? gt0 : gtr;
    st[((size_t)t * ST_WORDS + n) * 2]     = d;    // coalesced 16B/thread
    st[((size_t)t * ST_WORDS + n) * 2 + 1] = g;
  }
}

// ---- 64x64 bit transpose: lane l holds row l; returns lane b holding column b ----
__device__ __forceinline__ u64 bit_transpose64(u64 w, int lane) {
  const u64 LO0 = 0x00000000FFFFFFFFull, LO1 = 0x0000FFFF0000FFFFull,
            LO2 = 0x00FF00FF00FF00FFull, LO3 = 0x0F0F0F0F0F0F0F0Full,
            LO4 = 0x3333333333333333ull, LO5 = 0x5555555555555555ull;
#define XP_STAGE(d, LO)                                                  \
  {                                                                      \
    u64 p = (u64)__shfl_xor((long long)w, (d), 64);                      \
    if (lane & (d)) w = ((p >> (d)) & (LO)) | (w & ~(LO));               \
    else            w = (w & (LO)) | ((p << (d)) & ~(LO));               \
  }
  XP_STAGE(32, LO0) XP_STAGE(16, LO1) XP_STAGE(8, LO2)
  XP_STAGE(4,  LO3) XP_STAGE(2,  LO4) XP_STAGE(1, LO5)
#undef XP_STAGE
  return w;
}

// ---------------- persistent reservoir: 128 self-timed steps ----------------
__global__ __launch_bounds__(NTHR, 4) void reservoir_kernel(
    const int* __restrict__ lut, const int* __restrict__ adj,
    const int* __restrict__ mask, u64* __restrict__ st,
    unsigned* __restrict__ bar) {
  const int bi = blockIdx.x;
  const int tid = threadIdx.x;
  const int wave = tid >> 6, lane = tid & 63;

  // ---- last block = pacemaker (v4's leader relay, concurrent with compute) ----
  if (bi == NCOMP) {
    if (wave == 0) {
      for (unsigned r = 1; r <= NWIN - 2; ++r) {        // publish go = 1..30
        const unsigned tgt = r * (NCOMP / BAR_CNT);     // 8 arrivals/counter
        for (;;) {
          unsigned c = ALOAD(&bar[lane * BAR_STRIDE]);
          if (__all(c >= tgt)) break;
          __builtin_amdgcn_s_sleep(2);
        }
        if (lane < GO_CNT)
          ASTORE(&bar[(BAR_CNT + lane) * BAR_STRIDE], r);
      }
    }
    return;
  }

  __shared__ u64 lut_lds[NPB_PAD * 64];        // 20480 B
  __shared__ int adj_lds[NPB_PAD * K_MAX];     //  1920 B
  __shared__ unsigned char hn_lds[NPB_PAD];
  __shared__ unsigned warr[NWIN];              // per-window arrival counts
  __shared__ unsigned go_lds;                  // block-local go broadcast

  const int base = N_INPUT + bi * NPB;
  const int nloc = min(NPB, N_NODES - base);   // last compute block: 7

  if (tid < NWIN) warr[tid] = 0u;
  if (tid == 0) go_lds = 0u;

  // ---- prologue: adjacency (slot-REVERSED: slot j at offset 11-j) + hn ----
  if (tid < NPB_PAD) {
    int i = tid, h = 0;
    if (i < nloc) {
      for (int j = 0; j < K_MAX; j++) {
        int m = mask[(size_t)(base + i) * K_MAX + j];
        int a = adj[(size_t)(base + i) * K_MAX + j];
        adj_lds[i * K_MAX + (K_MAX - 1 - j)] = m ? a : DUMMY_NODE;
        h |= m;
      }
    } else {
      for (int j = 0; j < K_MAX; j++) adj_lds[i * K_MAX + j] = DUMMY_NODE;
    }
    hn_lds[i] = (unsigned char)(h ? 1 : 0);
  }

  // ---- prologue: pack this block's LUT slice into LDS (proven v4 path) ----
  const int nwords = nloc * 64;
  const int* lp = lut + (size_t)base * 4096;
  for (int w0 = wave * 8; w0 < nwords; w0 += 64) {
    int v[8];
#pragma unroll
    for (int q = 0; q < 8; q++) {
      int widx = w0 + q;
      v[q] = (widx < nwords) ? lp[(size_t)widx * 64 + lane] : 0;   // coalesced 256B
    }
#pragma unroll
    for (int q = 0; q < 8; q++) {
      int widx = w0 + q;
      u64 bal = __ballot(v[q] != 0);
      if (lane == 0 && widx < nwords) lut_lds[widx] = bal;
    }
  }
  __syncthreads();   // block-local only; after this waves free-run

  const int l0 = wave * 5;                     // this wave's first local node
  const int cnt = min(5, nloc - l0);           // may be <= 0

  int a0 = DUMMY_NODE;
  if (lane < 60) a0 = adj_lds[l0 * K_MAX + lane];
  unsigned hmask = 0;
#pragma unroll
  for (int i = 0; i < 5; i++) hmask |= (unsigned)hn_lds[l0 + i] << i;

  unsigned* cntp = &bar[(bi & (BAR_CNT - 1)) * BAR_STRIDE];
  unsigned* gop  = &bar[(BAR_CNT + (bi & (GO_CNT - 1))) * BAR_STRIDE];

  // ---- 128 self-timed steps ----
  for (int t = 0; t < T_STEPS; t++) {
    u64* stc = st + (size_t)t * ST_WORDS * 2;
    u64* stn = st + (size_t)(t + 1) * ST_WORDS * 2;

    // gather + validate: lanes >= 60 preset valid (no load, bits unused)
    u64 d = 0, g = KTAG;
    if (lane < 60) {
      d = ALOAD(&stc[2 * a0]);
      g = ALOAD(&stc[2 * a0 + 1]);
    }
    int rounds = 0;
    while (!__all((d ^ g) == KTAG)) {
      if (++rounds > 2) __builtin_amdgcn_s_sleep(1);
      if ((d ^ g) != KTAG) {                   // exec-masked reload
        d = ALOAD(&stc[2 * a0]);
        g = ALOAD(&stc[2 * a0 + 1]);
      }
    }
    u64 w = bit_transpose64(d, lane);          // lane b: 60 index bits for batch b

#pragma unroll
    for (int i = 0; i < 5; i++) {
      if (i < cnt) {                           // wave-uniform
        unsigned idx = (unsigned)(w >> (12 * i)) & 0xFFFu;   // MSB-first index
        u64 gl = lut_lds[(l0 + i) * 64 + (idx >> 6)];
        u64 res = __ballot((gl >> (idx & 63)) & 1ull);
        if (((hmask >> i) & 1u) && lane < 2) { // lane0: D, lane1: G (parallel)
          u64 val = lane ? (res ^ KTAG) : res;
          ASTORE(&stn[2 * (base + l0 + i) + lane], val);
        }
      }
    }

    // ---- window boundary: LDS-aggregated arrival + lagged LDS-broadcast gate ----
    if ((t & (PACE - 1)) == (PACE - 1) && t != T_STEPS - 1) {
      const int wnd = t / PACE;                // finished window wnd (0..30)
      unsigned old = 0;
      if (lane == 0) old = atomicAdd(&warr[wnd], 1u);
      old = (unsigned)__shfl((int)old, 0);
      if (old == 7u) {                         // this wave = block's master(wnd)
        if (lane == 0) {
          __hip_atomic_fetch_add(cntp, 1u, __ATOMIC_RELAXED, __HIP_MEMORY_SCOPE_AGENT);
          if (wnd >= 1) {
            while (ALOAD(gop) < (unsigned)wnd)
              __builtin_amdgcn_s_sleep(2);
            __hip_atomic_store(&go_lds, (unsigned)wnd,
                               __ATOMIC_RELAXED, __HIP_MEMORY_SCOPE_WORKGROUP);
          }
        }
      } else if (wnd >= 1) {
        while (__hip_atomic_load(&go_lds, __ATOMIC_RELAXED,
                                 __HIP_MEMORY_SCOPE_WORKGROUP) < (unsigned)wnd)
          __builtin_amdgcn_s_sleep(1);
      }
    }
  }
}

// ---- readout part: partial[c][o][b] = sum over chunk c of W[o][n]*bit(n,b) ----
__global__ __launch_bounds__(256) void readout_part(const u64* __restrict__ st128,
                                                    const float* __restrict__ Wout,
                                                    float* __restrict__ partial) {
  const int c = blockIdx.x / N_OUT;            // 0..31
  const int o = blockIdx.x % N_OUT;
  const int b = threadIdx.x & 63, k = threadIdx.x >> 6;   // lane = batch
  const int n0 = c * RO_NPC, n1 = n0 + RO_NPC;
  float acc = 0.f;
  for (int n = n0 + k; n < n1; n += 4) {
    u64 s = st128[2 * (N_INPUT + n)];          // D half; wave-uniform broadcast
    float w = Wout[(size_t)o * N_FEAT + n];
    acc += ((s >> b) & 1ull) ? w : 0.f;
  }
  __shared__ float red[4][64];
  red[k][b] = acc;
  __syncthreads();
  if (threadIdx.x < 64) {
    float tot = red[0][b] + red[1][b] + red[2][b] + red[3][b];
    partial[((size_t)c * N_OUT + o) * 64 + b] = tot;
  }
}

// ---- readout final: out[b][o] = sigmoid(sum_c partial + bias) ----
__global__ __launch_bounds__(640) void readout_final(const float* __restrict__ partial,
                                                     const float* __restrict__ bout,
                                                     float* __restrict__ out) {
  const int b = threadIdx.x & 63, o = threadIdx.x >> 6;   // 640 threads
  float tot = bout[o];
  for (int c = 0; c < RO_CHUNK; c++)
    tot += partial[((size_t)c * N_OUT + o) * 64 + b];
  out[(size_t)b * N_OUT + o] = 1.f / (1.f + __expf(-tot));
}

extern "C" void kernel_launch(void* const* d_in, const int* in_sizes, int n_in,
                              void* d_out, int out_size, void* d_ws, size_t ws_size,
                              hipStream_t stream) {
  const int* x    = (const int*)d_in[0];
  const int* w_in = (const int*)d_in[1];
  const int* adj  = (const int*)d_in[2];
  const int* mask = (const int*)d_in[3];
  const int* lut  = (const int*)d_in[4];
  const int* inis = (const int*)d_in[5];
  const float* Wout = (const float*)d_in[6];
  const float* bout = (const float*)d_in[7];
  float* out = (float*)d_out;

  char* ws = (char*)d_ws;
  size_t off = 0;
  auto alloc = [&](size_t bytes) -> void* {
    void* p = ws + off;
    off += (bytes + 255) & ~(size_t)255;
    return p;
  };
  u64* st_all = (u64*)alloc((size_t)T_BUF * ST_WORDS * 16);   // 41.3 MB (pairs)
  u64* xp     = (u64*)alloc((size_t)T_STEPS * N_BATCH * 8);
  u64* wcol   = (u64*)alloc(64 * 8);
  unsigned* bar = (unsigned*)alloc((size_t)(BAR_CNT + GO_CNT) * BAR_STRIDE * 4);
  float* partial = (float*)alloc((size_t)RO_CHUNK * N_OUT * 64 * 4);  // 80 KB
  (void)ws_size; (void)in_sizes; (void)n_in; (void)out_size;

  hipLaunchKernelGGL(pack_x_kernel, dim3(T_STEPS), dim3(256), 0, stream, x, xp);
  hipLaunchKernelGGL(init_kernel, dim3(2), dim3(256), 0, stream, w_in, wcol, bar);
  hipLaunchKernelGGL(fill_kernel, dim3(39, 33), dim3(512), 0, stream,
                     mask, inis, st_all);
  hipLaunchKernelGGL(u_pre_kernel, dim3(T_STEPS), dim3(64), 0, stream,
                     xp, wcol, st_all);

  hipLaunchKernelGGL(reservoir_kernel, dim3(NBLK), dim3(NTHR), 0, stream,
                     lut, adj, mask, st_all, bar);

  // final states live in st[128] (D halves)
  hipLaunchKernelGGL(readout_part, dim3(RO_CHUNK * N_OUT), dim3(256), 0, stream,
                     st_all + (size_t)T_STEPS * ST_WORDS * 2, Wout, partial);
  hipLaunchKernelGGL(readout_final, dim3(1), dim3(640), 0, stream,
                     partial, bout, out);
}

// Round 9
// 967.520 us; speedup vs baseline: 3.9787x; 1.8497x over previous
//
#include <hip/hip_runtime.h>
#include <cstdint>
#include <cstddef>

// BooleanReservoir — persistent kernel, v12 = R1-best (964 us total / 590 us
// reservoir, the session's best measurement) restored EXACTLY, plus launch-chain
// fusion: pack_x + init + u_pre merged into ONE prep kernel (each block
// recomputes wcol locally -> no cross-block deps; xp/wcol buffers dropped).
// 6 launches -> 4. Readout = R4's split version (measured neutral, fewer bytes).
// Verdict from R5-R8: self-timed dataflow loses (best 10.9 us/step vs 4.15 for
// the rendezvous; tag pairs double the scarce scattered-request traffic and
// polling quantizes handoffs at ~1 RTT). Rendezvous step ~4.15 us is invariant
// across 4 barrier topologies -> keep R1's exact barrier.

#define N_NODES   20000
#define N_INPUT   64
#define K_MAX     12
#define T_STEPS   128
#define N_BATCH   64
#define N_OUT     10
#define N_FEAT    (N_NODES - N_INPUT)   // 19936
#define DUMMY_NODE 20000                // always-zero state word
#define ST_WORDS  20004

#define NBLK 512
#define NTHR 512                        // 8 waves/block, 2 blocks/CU
#define NPB  39                         // 512*39 = 19968 >= 19936
#define NPB_PAD 40                      // 8 waves * 5 nodes
#define BAR_CNT 64                      // distributed arrival counters
#define GO_CNT  8                       // go-flags (release fan-out)
#define BAR_STRIDE 32                   // u32 units -> 128 B apart

#define RO_CHUNK 32                     // 19936 = 32 * 623
#define RO_NPC   623

typedef unsigned long long u64;

// ---- fused prep: blocks 0..127 -> xp(t)+wcol+u(t); 128..206 -> state init;
// ---- block 207 -> barrier zeroing. No cross-block dependencies.
__global__ __launch_bounds__(256) void prep_kernel(const int* __restrict__ x,
                                                   const int* __restrict__ w_in,
                                                   const int* __restrict__ inis,
                                                   u64* __restrict__ buf0,
                                                   u64* __restrict__ buf1,
                                                   u64* __restrict__ u_all,
                                                   unsigned* __restrict__ bar) {
  const int wave = threadIdx.x >> 6, lane = threadIdx.x & 63;
  if (blockIdx.x < T_STEPS) {
    const int t = blockIdx.x;
    __shared__ u64 xp_lds[N_BATCH];          // xp[t][b]
    __shared__ u64 wcol_lds[64];             // input weight columns
    for (int b = wave; b < N_BATCH; b += 4) {
      int v = x[((size_t)b * T_STEPS + t) * 64 + lane];   // lane = bit j
      u64 bal = __ballot(v != 0);
      if (lane == 0) xp_lds[b] = bal;
    }
    for (int i = wave; i < 64; i += 4) {
      int wv = w_in[(size_t)lane * 64 + i];  // lane = j
      u64 wc = __ballot(wv != 0);
      if (lane == 0) wcol_lds[i] = wc;
    }
    __syncthreads();
    u64 xw = xp_lds[lane];                   // lane = batch b
    for (int i = wave; i < 64; i += 4) {
      u64 ub = __ballot((xw & wcol_lds[i]) != 0);   // u(t)[b][i]
      if (lane == 0) {
        if (t == 0) buf0[i] = ub;            // u(0) seeds step 0's gather
        else        u_all[(size_t)t * 64 + i] = ub;
      }
    }
  } else if (blockIdx.x < T_STEPS + 79) {
    int n = (blockIdx.x - T_STEPS) * 256 + threadIdx.x;
    if (n >= N_INPUT && n < ST_WORDS) {
      u64 w = (n < N_NODES && inis[n] != 0) ? ~0ull : 0ull;   // dummy/pad -> 0
      buf0[n] = w;
      buf1[n] = w;   // no-neigh nodes never rewritten: init lives in both buffers
    }
  } else {
    if (threadIdx.x < BAR_CNT + GO_CNT)      // ws re-poisoned each call
      bar[threadIdx.x * BAR_STRIDE] = 0u;
  }
}

// ---- 64x64 bit transpose: lane l holds row l; returns lane b holding column b ----
__device__ __forceinline__ u64 bit_transpose64(u64 w, int lane) {
  const u64 LO0 = 0x00000000FFFFFFFFull, LO1 = 0x0000FFFF0000FFFFull,
            LO2 = 0x00FF00FF00FF00FFull, LO3 = 0x0F0F0F0F0F0F0F0Full,
            LO4 = 0x3333333333333333ull, LO5 = 0x5555555555555555ull;
#define XP_STAGE(d, LO)                                                  \
  {                                                                      \
    u64 p = (u64)__shfl_xor((long long)w, (d), 64);                      \
    if (lane & (d)) w = ((p >> (d)) & (LO)) | (w & ~(LO));               \
    else            w = (w & (LO)) | ((p << (d)) & ~(LO));               \
  }
  XP_STAGE(32, LO0) XP_STAGE(16, LO1) XP_STAGE(8, LO2)
  XP_STAGE(4,  LO3) XP_STAGE(2,  LO4) XP_STAGE(1, LO5)
#undef XP_STAGE
  return w;
}

// ---------------- persistent reservoir: all 128 steps (R1-exact) ----------------
__global__ __launch_bounds__(NTHR, 4) void reservoir_kernel(
    const int* __restrict__ lut, const int* __restrict__ adj,
    const int* __restrict__ mask, const u64* __restrict__ u_all,
    u64* __restrict__ buf0, u64* __restrict__ buf1,
    unsigned* __restrict__ bar) {
  __shared__ u64 lut_lds[NPB_PAD * 64];        // 20480 B
  __shared__ int adj_lds[NPB_PAD * K_MAX];     //  1920 B
  __shared__ unsigned char hn_lds[NPB_PAD];

  const int bi = blockIdx.x;
  const int tid = threadIdx.x;
  const int wave = tid >> 6, lane = tid & 63;
  const int base = N_INPUT + bi * NPB;
  const int nloc = min(NPB, N_NODES - base);   // last block: 7

  // ---- prologue: adjacency (slot-REVERSED: slot j at offset 11-j) + hn ----
  // After transpose, lane b's bit (12i + (11-j)) = neighbor j -> the 12-bit
  // field (w >> 12i) & 0xFFF is directly the reference's MSB-first LUT index.
  if (tid < NPB_PAD) {
    int i = tid, h = 0;
    if (i < nloc) {
      for (int j = 0; j < K_MAX; j++) {
        int m = mask[(size_t)(base + i) * K_MAX + j];
        int a = adj[(size_t)(base + i) * K_MAX + j];
        adj_lds[i * K_MAX + (K_MAX - 1 - j)] = m ? a : DUMMY_NODE;
        h |= m;
      }
    } else {
      for (int j = 0; j < K_MAX; j++) adj_lds[i * K_MAX + j] = DUMMY_NODE;
    }
    hn_lds[i] = (unsigned char)(h ? 1 : 0);
  }

  // ---- prologue: pack this block's LUT slice into LDS (natural entry order) ----
  const int nwords = nloc * 64;
  const int* lp = lut + (size_t)base * 4096;
  for (int w0 = wave * 8; w0 < nwords; w0 += 64) {
    int v[8];
#pragma unroll
    for (int q = 0; q < 8; q++) {
      int widx = w0 + q;
      v[q] = (widx < nwords) ? lp[(size_t)widx * 64 + lane] : 0;   // coalesced 256B
    }
#pragma unroll
    for (int q = 0; q < 8; q++) {
      int widx = w0 + q;
      u64 bal = __ballot(v[q] != 0);
      if (lane == 0 && widx < nwords) lut_lds[widx] = bal;
    }
  }
  __syncthreads();   // block-local; step 0 reads prep's buf0 (launch-ordered)

  const int l0 = wave * 5;                     // this wave's first local node
  const int cnt = min(5, nloc - l0);           // may be <= 0

  // step-invariant per-wave state (hoisted out of the t-loop):
  int my_a = DUMMY_NODE;                       // lanes 60-63 gather the 0-word
  if (lane < 60) my_a = adj_lds[l0 * K_MAX + lane];
  unsigned hmask = 0;
#pragma unroll
  for (int i = 0; i < 5; i++) hmask |= (unsigned)hn_lds[l0 + i] << i;

  // ---- 128 steps ----
  for (int t = 0; t < T_STEPS; t++) {
    u64* cur = (t & 1) ? buf1 : buf0;
    u64* nxt = (t & 1) ? buf0 : buf1;

    // gather: lane l (<60) -> neighbor word for (node l/12, rev-slot l%12)
    u64 w = __hip_atomic_load(&cur[my_a], __ATOMIC_RELAXED,
                              __HIP_MEMORY_SCOPE_AGENT);
    // transpose: lane b now holds all 60 index bits for batch b
    w = bit_transpose64(w, lane);

#pragma unroll
    for (int i = 0; i < 5; i++) {
      if (i < cnt) {                           // wave-uniform
        unsigned idx = (unsigned)(w >> (12 * i)) & 0xFFFu;   // MSB-first index
        u64 g = lut_lds[(l0 + i) * 64 + (idx >> 6)];
        u64 res = __ballot((g >> (idx & 63)) & 1ull);
        if (lane == 0 && ((hmask >> i) & 1u))
          __hip_atomic_store(&nxt[base + l0 + i], res,
                             __ATOMIC_RELAXED, __HIP_MEMORY_SCOPE_AGENT);
      }
    }

    // u(t+1) -> nxt[0..63]: last block's wave 7 (idle there: nloc=7), 64-lane copy
    if (bi == NBLK - 1 && wave == 7 && t + 1 < T_STEPS) {
      u64 uw = u_all[(size_t)(t + 1) * 64 + lane];           // plain coalesced load
      __hip_atomic_store(&nxt[lane], uw, __ATOMIC_RELAXED, __HIP_MEMORY_SCOPE_AGENT);
    }

    // ---- hierarchical grid barrier (R1-exact: fetch_add + leader + go) ----
    if (t != T_STEPS - 1) {
      __syncthreads();   // each wave drains its vmcnt: stores are at L3
      __builtin_amdgcn_fence(__ATOMIC_RELEASE, "workgroup");  // compiler ordering
      if (tid == 0)
        __hip_atomic_fetch_add(&bar[(bi & (BAR_CNT - 1)) * BAR_STRIDE], 1u,
                               __ATOMIC_RELAXED, __HIP_MEMORY_SCOPE_AGENT);
      if (bi == 0 && wave == 0) {
        // leader: lane l polls counter l (one 64-lane load per round)
        const unsigned tgt = (unsigned)(t + 1) * (NBLK / BAR_CNT);
        for (;;) {
          unsigned c = __hip_atomic_load(&bar[lane * BAR_STRIDE],
                                         __ATOMIC_RELAXED, __HIP_MEMORY_SCOPE_AGENT);
          if (__all(c >= tgt)) break;
        }
        if (lane < GO_CNT)
          __hip_atomic_store(&bar[(BAR_CNT + lane) * BAR_STRIDE], (unsigned)(t + 1),
                             __ATOMIC_RELAXED, __HIP_MEMORY_SCOPE_AGENT);
      } else if (wave == 0) {
        // all lanes load the SAME go-flag -> one L3 request per round
        unsigned* gp = &bar[(BAR_CNT + (bi & (GO_CNT - 1))) * BAR_STRIDE];
        while (__hip_atomic_load(gp, __ATOMIC_RELAXED, __HIP_MEMORY_SCOPE_AGENT)
               < (unsigned)(t + 1)) { /* spin */ }
      }
      __builtin_amdgcn_fence(__ATOMIC_ACQUIRE, "workgroup");  // compiler ordering
      __syncthreads();
    }
  }
}

// ---- readout part: partial[c][o][b] = sum over chunk c of W[o][n]*bit(n,b) ----
__global__ __launch_bounds__(256) void readout_part(const u64* __restrict__ st,
                                                    const float* __restrict__ Wout,
                                                    float* __restrict__ partial) {
  const int c = blockIdx.x / N_OUT;            // 0..31
  const int o = blockIdx.x % N_OUT;
  const int b = threadIdx.x & 63, k = threadIdx.x >> 6;   // lane = batch
  const int n0 = c * RO_NPC, n1 = n0 + RO_NPC;
  float acc = 0.f;
  for (int n = n0 + k; n < n1; n += 4) {
    u64 s = st[N_INPUT + n];                   // wave-uniform addr -> broadcast
    float w = Wout[(size_t)o * N_FEAT + n];
    acc += ((s >> b) & 1ull) ? w : 0.f;
  }
  __shared__ float red[4][64];
  red[k][b] = acc;
  __syncthreads();
  if (threadIdx.x < 64) {
    float tot = red[0][b] + red[1][b] + red[2][b] + red[3][b];
    partial[((size_t)c * N_OUT + o) * 64 + b] = tot;
  }
}

// ---- readout final: out[b][o] = sigmoid(sum_c partial + bias) ----
__global__ __launch_bounds__(640) void readout_final(const float* __restrict__ partial,
                                                     const float* __restrict__ bout,
                                                     float* __restrict__ out) {
  const int b = threadIdx.x & 63, o = threadIdx.x >> 6;   // 640 threads
  float tot = bout[o];
  for (int c = 0; c < RO_CHUNK; c++)
    tot += partial[((size_t)c * N_OUT + o) * 64 + b];
  out[(size_t)b * N_OUT + o] = 1.f / (1.f + __expf(-tot));
}

extern "C" void kernel_launch(void* const* d_in, const int* in_sizes, int n_in,
                              void* d_out, int out_size, void* d_ws, size_t ws_size,
                              hipStream_t stream) {
  const int* x    = (const int*)d_in[0];
  const int* w_in = (const int*)d_in[1];
  const int* adj  = (const int*)d_in[2];
  const int* mask = (const int*)d_in[3];
  const int* lut  = (const int*)d_in[4];
  const int* inis = (const int*)d_in[5];
  const float* Wout = (const float*)d_in[6];
  const float* bout = (const float*)d_in[7];
  float* out = (float*)d_out;

  char* ws = (char*)d_ws;
  size_t off = 0;
  auto alloc = [&](size_t bytes) -> void* {
    void* p = ws + off;
    off += (bytes + 255) & ~(size_t)255;
    return p;
  };
  u64* buf0 = (u64*)alloc((size_t)ST_WORDS * 8);
  u64* buf1 = (u64*)alloc((size_t)ST_WORDS * 8);
  u64* u_all = (u64*)alloc((size_t)T_STEPS * 64 * 8);         // 64 KB
  unsigned* bar = (unsigned*)alloc((size_t)(BAR_CNT + GO_CNT) * BAR_STRIDE * 4);
  float* partial = (float*)alloc((size_t)RO_CHUNK * N_OUT * 64 * 4);  // 80 KB
  (void)ws_size; (void)in_sizes; (void)n_in; (void)out_size;

  hipLaunchKernelGGL(prep_kernel, dim3(T_STEPS + 79 + 1), dim3(256), 0, stream,
                     x, w_in, inis, buf0, buf1, u_all, bar);

  hipLaunchKernelGGL(reservoir_kernel, dim3(NBLK), dim3(NTHR), 0, stream,
                     lut, adj, mask, u_all, buf0, buf1, bar);

  // T even -> final states in buf0
  hipLaunchKernelGGL(readout_part, dim3(RO_CHUNK * N_OUT), dim3(256), 0, stream,
                     buf0, Wout, partial);
  hipLaunchKernelGGL(readout_final, dim3(1), dim3(640), 0, stream,
                     partial, bout, out);
}